// Round 1
// baseline (565.686 us; speedup 1.0000x reference)
//
#include <hip/hip_runtime.h>

typedef __attribute__((ext_vector_type(8))) short short8;
typedef __attribute__((ext_vector_type(4))) float f32x4;

// async global->LDS, 16B per lane. Dest is wave-uniform base + lane*16 (m104).
#define GLL16(gp, lp) __builtin_amdgcn_global_load_lds( \
    (__attribute__((address_space(1))) void*)(gp), \
    (__attribute__((address_space(3))) void*)(lp), 16, 0, 0)

__device__ __forceinline__ unsigned short f2b(float f) {
  unsigned int u = __builtin_bit_cast(unsigned int, f);
  u += 0x7fffu + ((u >> 16) & 1u);   // RNE; inputs are finite
  return (unsigned short)(u >> 16);
}
__device__ __forceinline__ float b2f(unsigned short s) {
  unsigned int u = ((unsigned int)s) << 16;
  return __builtin_bit_cast(float, u);
}

// ---------------- f32 -> bf16 straight convert (Xd, Xo) ----------------
__global__ __launch_bounds__(256) void conv_k(const float* __restrict__ in,
                                              short8* __restrict__ out, long n8) {
  for (long i = (long)blockIdx.x * 256 + threadIdx.x; i < n8;
       i += (long)gridDim.x * 256) {
    const float4* p = (const float4*)in + 2 * i;
    float4 a = p[0], b = p[1];
    short8 v;
    v[0] = (short)f2b(a.x); v[1] = (short)f2b(a.y);
    v[2] = (short)f2b(a.z); v[3] = (short)f2b(a.w);
    v[4] = (short)f2b(b.x); v[5] = (short)f2b(b.y);
    v[6] = (short)f2b(b.z); v[7] = (short)f2b(b.w);
    out[i] = v;
  }
}

// ------------- transpose+convert weights: in (K x C f32) -> out (C x K bf16) -------------
// inter=1 (Wv): output row for input col c = 4*(c&1023) + (c>>10)  (p = 4d+h head-interleave)
__global__ __launch_bounds__(256) void tconv_k(const float* __restrict__ in,
                                               unsigned short* __restrict__ out,
                                               int K, int C, int inter) {
  __shared__ float t[32][33];
  int k0 = blockIdx.x * 32, c0 = blockIdx.y * 32;
  int tx = threadIdx.x & 31, ty = threadIdx.x >> 5;
#pragma unroll
  for (int p = 0; p < 4; ++p)
    t[ty + p * 8][tx] = in[(size_t)(k0 + ty + p * 8) * C + c0 + tx];
  __syncthreads();
#pragma unroll
  for (int p = 0; p < 4; ++p) {
    int c = ty + p * 8;
    int gc = c0 + c;
    int orow = inter ? ((gc & 1023) * 4 + (gc >> 10)) : gc;
    out[(size_t)orow * K + k0 + tx] = f2b(t[tx][c]);
  }
}

// ---------------- unified 128x128 GEMM, BK=64, 4 waves (m97 structure) ----------------
// A: rows (row stride = KD bf16).  Bt: output-cols as rows (row stride = KD bf16).
// EPI 0: out bf16 = acc + bias[col]            (Q GEMM)
// EPI 1: scores[row][ntile] = sum_col (acc+bk[col]) * Qb[row][col]   (K GEMM + reduce)
// EPI 2: Z[row][d] = max_h s[row][h]*(acc+bv) with p=4d+h interleave (V GEMM fused)
template <int KD, int EPI>
__global__ __launch_bounds__(256) void gemm_k(
    const unsigned short* __restrict__ A, const unsigned short* __restrict__ Bt,
    const float* __restrict__ bias, const unsigned short* __restrict__ Qb,
    unsigned short* __restrict__ outb, float* __restrict__ sc,
    float* __restrict__ Z) {
  __shared__ __align__(16) unsigned short As[128 * 64];
  __shared__ __align__(16) unsigned short Bs[128 * 64];
  __shared__ float s_sc[512];
  __shared__ float sred[128][2];

  int tid = threadIdx.x;
  int bid = blockIdx.x;
  int ntile, mtile;
  if constexpr (EPI == 2) {
    int cpx = gridDim.x >> 3;                 // grid % 8 == 0 (bijective XCD swizzle)
    int lb = (bid & 7) * cpx + (bid >> 3);
    ntile = lb & 31;
    mtile = lb >> 5;
  } else {
    ntile = bid & 3;
    mtile = bid >> 2;
  }
  int l = tid & 63, wid = tid >> 6, wm = wid >> 1, wn = wid & 1;
  int m0 = mtile * 128;

  if constexpr (EPI == 2) {
    for (int i = tid; i < 512; i += 256) s_sc[i] = sc[(size_t)m0 * 4 + i];
  }

  const unsigned short* Ab = A + (size_t)m0 * KD;
  const unsigned short* Bb = Bt + (size_t)ntile * 128 * KD;

  f32x4 zero = {0.f, 0.f, 0.f, 0.f};
  f32x4 acc[4][4];
#pragma unroll
  for (int m = 0; m < 4; ++m)
#pragma unroll
    for (int n = 0; n < 4; ++n) acc[m][n] = zero;

  for (int kt = 0; kt < KD / 64; ++kt) {
    const unsigned short* sA = Ab + kt * 64;
    const unsigned short* sB = Bb + kt * 64;
#pragma unroll
    for (int p = 0; p < 4; ++p) {          // A tile: 128 rows x 64 k, swizzled source
      int row = p * 32 + wid * 8 + (l >> 3);
      int sch = (l & 7) ^ (row & 7);
      GLL16((const char*)(sA + (size_t)row * KD) + sch * 16,
            (char*)As + p * 4096 + wid * 1024);
    }
#pragma unroll
    for (int p = 0; p < 4; ++p) {          // B tile
      int row = p * 32 + wid * 8 + (l >> 3);
      int sch = (l & 7) ^ (row & 7);
      GLL16((const char*)(sB + (size_t)row * KD) + sch * 16,
            (char*)Bs + p * 4096 + wid * 1024);
    }
    __syncthreads();
#pragma unroll
    for (int ks = 0; ks < 2; ++ks) {
      short8 af[4], bfr[4];
#pragma unroll
      for (int m = 0; m < 4; ++m) {
        int row = wm * 64 + m * 16 + (l & 15);
        int kc = ks * 4 + (l >> 4);
        af[m] = *(const short8*)((const char*)As + row * 128 +
                                 ((kc ^ (row & 7)) << 4));
      }
#pragma unroll
      for (int n = 0; n < 4; ++n) {
        int row = wn * 64 + n * 16 + (l & 15);
        int kc = ks * 4 + (l >> 4);
        bfr[n] = *(const short8*)((const char*)Bs + row * 128 +
                                  ((kc ^ (row & 7)) << 4));
      }
#pragma unroll
      for (int m = 0; m < 4; ++m)
#pragma unroll
        for (int n = 0; n < 4; ++n)
          acc[m][n] = __builtin_amdgcn_mfma_f32_16x16x32_bf16(af[m], bfr[n],
                                                              acc[m][n], 0, 0, 0);
    }
    __syncthreads();
  }

  if constexpr (EPI == 0) {
#pragma unroll
    for (int n = 0; n < 4; ++n) {
      int col = ntile * 128 + wn * 64 + n * 16 + (l & 15);
      float bb = bias[col];
#pragma unroll
      for (int m = 0; m < 4; ++m) {
        int rowb = m0 + wm * 64 + m * 16 + ((l >> 4) << 2);
#pragma unroll
        for (int r = 0; r < 4; ++r)
          outb[(size_t)(rowb + r) * 512 + col] = f2b(acc[m][n][r] + bb);
      }
    }
  } else if constexpr (EPI == 1) {
    float part[4][4] = {};
#pragma unroll
    for (int n = 0; n < 4; ++n) {
      int col = ntile * 128 + wn * 64 + n * 16 + (l & 15);
      float bb = bias[col];
#pragma unroll
      for (int m = 0; m < 4; ++m) {
        int rowb = m0 + wm * 64 + m * 16 + ((l >> 4) << 2);
#pragma unroll
        for (int r = 0; r < 4; ++r) {
          float kv = acc[m][n][r] + bb;
          part[m][r] += kv * b2f(Qb[(size_t)(rowb + r) * 512 + col]);
        }
      }
    }
#pragma unroll
    for (int m = 0; m < 4; ++m)
#pragma unroll
      for (int r = 0; r < 4; ++r) {
        float s = part[m][r];
        s += __shfl_xor(s, 1);
        s += __shfl_xor(s, 2);
        s += __shfl_xor(s, 4);
        s += __shfl_xor(s, 8);
        if ((l & 15) == 0)
          sred[wm * 64 + m * 16 + ((l >> 4) << 2) + r][wn] = s;
      }
    __syncthreads();
    if (tid < 128) sc[(size_t)(m0 + tid) * 4 + ntile] = sred[tid][0] + sred[tid][1];
  } else {
    float* Zs = (float*)As;                 // 128x32 f32 = 16 KB, reuse A LDS
#pragma unroll
    for (int n = 0; n < 4; ++n) {
      int pl = wn * 64 + n * 16 + (l & 15); // local permuted col, p = 4d+h
      int pg = ntile * 128 + pl;
      int h = pl & 3;
      float bb = bias[(pg & 3) * 1024 + (pg >> 2)];
#pragma unroll
      for (int m = 0; m < 4; ++m) {
        int rl = wm * 64 + m * 16 + ((l >> 4) << 2);
#pragma unroll
        for (int r = 0; r < 4; ++r) {
          float z = s_sc[(rl + r) * 4 + h] * (acc[m][n][r] + bb);
          z = fmaxf(z, __shfl_xor(z, 1));   // max over heads (adjacent p)
          z = fmaxf(z, __shfl_xor(z, 2));
          if ((l & 3) == 0) Zs[(rl + r) * 32 + (pl >> 2)] = z;
        }
      }
    }
    __syncthreads();
#pragma unroll
    for (int p = 0; p < 4; ++p) {           // coalesced float4 stores
      int idx = p * 1024 + tid * 4;
      int row = idx >> 5, d = idx & 31;
      f32x4 v = *(const f32x4*)&Zs[idx];
      *(f32x4*)&Z[(size_t)(m0 + row) * 1024 + ntile * 32 + d] = v;
    }
  }
}

// ---------------- fallback (only if ws too small): fp32, correct but slow ----------------
__global__ __launch_bounds__(256) void naive_k(
    const float* __restrict__ Xd, const float* __restrict__ Xo,
    const float* __restrict__ Wq, const float* __restrict__ bq,
    const float* __restrict__ Wk, const float* __restrict__ bk,
    const float* __restrict__ Wv, const float* __restrict__ bv,
    float* __restrict__ Z) {
  int i = blockIdx.x, t = threadIdx.x;
  __shared__ float xd[1024], xo[512], s[4];
  for (int j = t; j < 1024; j += 256) xd[j] = Xd[(size_t)i * 1024 + j];
  for (int j = t; j < 512; j += 256) xo[j] = Xo[(size_t)i * 512 + j];
  if (t < 4) s[t] = 0.f;
  __syncthreads();
  for (int c = t; c < 512; c += 256) {
    float q = bq[c], k = bk[c];
    for (int j = 0; j < 512; ++j) q += xo[j] * Wq[(size_t)j * 512 + c];
    for (int j = 0; j < 1024; ++j) k += xd[j] * Wk[(size_t)j * 512 + c];
    atomicAdd(&s[c >> 7], q * k);
  }
  __syncthreads();
  for (int d = t; d < 1024; d += 256) {
    float z = -INFINITY;
    for (int h = 0; h < 4; ++h) {
      float v = bv[h * 1024 + d];
      for (int j = 0; j < 1024; ++j) v += xd[j] * Wv[(size_t)j * 4096 + h * 1024 + d];
      z = fmaxf(z, s[h] * v);
    }
    Z[(size_t)i * 1024 + d] = z;
  }
}

extern "C" void kernel_launch(void* const* d_in, const int* in_sizes, int n_in,
                              void* d_out, int out_size, void* d_ws, size_t ws_size,
                              hipStream_t stream) {
  const float* Xd = (const float*)d_in[0];
  const float* Xo = (const float*)d_in[1];
  const float* Wq = (const float*)d_in[2];
  const float* bq = (const float*)d_in[3];
  const float* Wk = (const float*)d_in[4];
  const float* bk = (const float*)d_in[5];
  const float* Wv = (const float*)d_in[6];
  const float* bv = (const float*)d_in[7];
  float* Z = (float*)d_out;
  long N = in_sizes[0] / 1024;

  size_t sz_Xd = (size_t)N * 1024 * 2, sz_Xo = (size_t)N * 512 * 2;
  size_t sz_Wq = (size_t)512 * 512 * 2, sz_Wk = (size_t)512 * 1024 * 2;
  size_t sz_Wv = (size_t)4096 * 1024 * 2;
  size_t sz_Qb = (size_t)N * 512 * 2, sz_sc = (size_t)N * 4 * 4;
  size_t o_Xo = sz_Xd, o_Wq = o_Xo + sz_Xo, o_Wk = o_Wq + sz_Wq,
         o_Wv = o_Wk + sz_Wk, o_Qb = o_Wv + sz_Wv, o_sc = o_Qb + sz_Qb;
  size_t need = o_sc + sz_sc;

  if (ws_size < need || (N % 128) != 0) {
    naive_k<<<(int)N, 256, 0, stream>>>(Xd, Xo, Wq, bq, Wk, bk, Wv, bv, Z);
    return;
  }

  char* w = (char*)d_ws;
  unsigned short* Xd_b = (unsigned short*)w;
  unsigned short* Xo_b = (unsigned short*)(w + o_Xo);
  unsigned short* Wq_t = (unsigned short*)(w + o_Wq);
  unsigned short* Wk_t = (unsigned short*)(w + o_Wk);
  unsigned short* Wv_p = (unsigned short*)(w + o_Wv);
  unsigned short* Qb   = (unsigned short*)(w + o_Qb);
  float* sc = (float*)(w + o_sc);

  conv_k<<<2048, 256, 0, stream>>>(Xd, (short8*)Xd_b, N * 1024 / 8);
  conv_k<<<2048, 256, 0, stream>>>(Xo, (short8*)Xo_b, N * 512 / 8);
  tconv_k<<<dim3(16, 16), 256, 0, stream>>>(Wq, Wq_t, 512, 512, 0);
  tconv_k<<<dim3(32, 16), 256, 0, stream>>>(Wk, Wk_t, 1024, 512, 0);
  tconv_k<<<dim3(32, 128), 256, 0, stream>>>(Wv, Wv_p, 1024, 4096, 1);

  int mt = (int)(N / 128);
  gemm_k<512, 0><<<mt * 4, 256, 0, stream>>>(Xo_b, Wq_t, bq, nullptr, Qb, nullptr, nullptr);
  gemm_k<1024, 1><<<mt * 4, 256, 0, stream>>>(Xd_b, Wk_t, bk, Qb, nullptr, sc, nullptr);
  gemm_k<1024, 2><<<mt * 32, 256, 0, stream>>>(Xd_b, Wv_p, bv, nullptr, nullptr, sc, Z);
}

// Round 2
// 533.878 us; speedup vs baseline: 1.0596x; 1.0596x over previous
//
#include <hip/hip_runtime.h>

typedef __attribute__((ext_vector_type(8))) short short8;
typedef __attribute__((ext_vector_type(4))) float f32x4;

// async global->LDS, 16B per lane. LDS dest = wave-uniform base (+ lane*16 by HW).
#define GLL16(gp, lp) __builtin_amdgcn_global_load_lds( \
    (__attribute__((address_space(1))) void*)(gp), \
    (__attribute__((address_space(3))) void*)(lp), 16, 0, 0)

__device__ __forceinline__ unsigned short f2b(float f) {
  unsigned int u = __builtin_bit_cast(unsigned int, f);
  u += 0x7fffu + ((u >> 16) & 1u);   // RNE; inputs are finite
  return (unsigned short)(u >> 16);
}
__device__ __forceinline__ float b2f(unsigned short s) {
  unsigned int u = ((unsigned int)s) << 16;
  return __builtin_bit_cast(float, u);
}

// ---------------- f32 -> bf16 straight convert (Xd, Xo) ----------------
__global__ __launch_bounds__(256) void conv_k(const float* __restrict__ in,
                                              short8* __restrict__ out, long n8) {
  for (long i = (long)blockIdx.x * 256 + threadIdx.x; i < n8;
       i += (long)gridDim.x * 256) {
    const float4* p = (const float4*)in + 2 * i;
    float4 a = p[0], b = p[1];
    short8 v;
    v[0] = (short)f2b(a.x); v[1] = (short)f2b(a.y);
    v[2] = (short)f2b(a.z); v[3] = (short)f2b(a.w);
    v[4] = (short)f2b(b.x); v[5] = (short)f2b(b.y);
    v[6] = (short)f2b(b.z); v[7] = (short)f2b(b.w);
    out[i] = v;
  }
}

// ------------- transpose+convert weights: in (K x C f32) -> out (C x K bf16) -------------
// inter=1 (Wv): output row for input col c = 4*(c&1023) + (c>>10)  (p = 4d+h head-interleave)
__global__ __launch_bounds__(256) void tconv_k(const float* __restrict__ in,
                                               unsigned short* __restrict__ out,
                                               int K, int C, int inter) {
  __shared__ float t[32][33];
  int k0 = blockIdx.x * 32, c0 = blockIdx.y * 32;
  int tx = threadIdx.x & 31, ty = threadIdx.x >> 5;
#pragma unroll
  for (int p = 0; p < 4; ++p)
    t[ty + p * 8][tx] = in[(size_t)(k0 + ty + p * 8) * C + c0 + tx];
  __syncthreads();
#pragma unroll
  for (int p = 0; p < 4; ++p) {
    int c = ty + p * 8;
    int gc = c0 + c;
    int orow = inter ? ((gc & 1023) * 4 + (gc >> 10)) : gc;
    out[(size_t)orow * K + k0 + tx] = f2b(t[tx][c]);
  }
}

// ======== 256x256 BK=64 8-wave phase-interleaved V-GEMM (T2+T3+T5), EPI=2 fused ========
// A: N x KD bf16 rows. Bt: 4096 permuted cols as rows (p=4d+h), stride KD.
// Z[row][d] = max_h sc[row][h] * (acc + bv) ; NT = 16 ntiles (4096/256).
template <int KD>
__global__ __launch_bounds__(512, 2) void gemm_v256_k(
    const unsigned short* __restrict__ A, const unsigned short* __restrict__ Bt,
    const float* __restrict__ bias, const float* __restrict__ sc,
    float* __restrict__ Z) {
  __shared__ __align__(16) unsigned short Ash[2][16384];  // 2 bufs x 256r x 64k
  __shared__ __align__(16) unsigned short Bsh[2][16384];
  __shared__ float s_sc[1024];

  int tid = threadIdx.x;
  int bid = blockIdx.x;
  int cpx = gridDim.x >> 3;                  // grid % 8 == 0 (bijective XCD swizzle)
  int lb = (bid & 7) * cpx + (bid >> 3);
  int mtile = lb >> 4, nt0 = lb & 15;
  long m0 = (long)mtile * 256;
  int l = tid & 63, wid = tid >> 6, wm = wid >> 2, wn = wid & 3;

  for (int i = tid; i < 1024; i += 512) s_sc[i] = sc[m0 * 4 + i];

  // staging source: row = tid>>3 within 64-row group, chunk = tid&7, pre-swizzled
  int rowg = tid >> 3;
  int srcOff = rowg * (KD * 2) + (((tid & 7) ^ (rowg & 7)) << 4);
  const char* aB = (const char*)(A + m0 * KD) + srcOff;
  const char* bB = (const char*)(Bt + (long)nt0 * 256 * KD) + srcOff;
  char* AshB = (char*)Ash;
  char* BshB = (char*)Bsh;
  int dstOff = wid * 1024;                   // wave-uniform dest base component

  auto stage = [&](int k, int bb) {          // one K-tile = 4 half-stages x 2 ops
#pragma unroll
    for (int h = 0; h < 2; ++h)
#pragma unroll
      for (int s = 0; s < 2; ++s) {
        int go = (h * 128 + s * 64) * (KD * 2) + k * 128;
        int lo = bb * 32768 + h * 16384 + s * 8192 + dstOff;
        GLL16(aB + go, AshB + lo);
        GLL16(bB + go, BshB + lo);
      }
  };

  f32x4 zero = {0.f, 0.f, 0.f, 0.f};
  f32x4 acc[8][4];
#pragma unroll
  for (int m = 0; m < 8; ++m)
#pragma unroll
    for (int n = 0; n < 4; ++n) acc[m][n] = zero;

  stage(0, 0);                               // prologue

  const int NKT = KD / 64;
  for (int kt = 0; kt < NKT; ++kt) {
    int b = kt & 1;
    // K-tile boundary: buf b's content must have landed (issued one K-tile ago)
    asm volatile("s_waitcnt vmcnt(0)" ::: "memory");
    __builtin_amdgcn_s_barrier();
    __builtin_amdgcn_sched_barrier(0);
    if (kt + 1 < NKT) stage(kt + 1, b ^ 1);  // issue next tile early (3-phase cover)

    const char* Al = AshB + b * 32768;
    const char* Bl = BshB + b * 32768;
    int ar = l & 15;
    int kc = l >> 4;
    short8 bf[2][4], af[4];
#pragma unroll
    for (int ks = 0; ks < 2; ++ks) {
#pragma unroll
      for (int mh = 0; mh < 2; ++mh) {
        if (mh == 0) {
#pragma unroll
          for (int n = 0; n < 4; ++n) {
            int row = wn * 64 + n * 16 + ar;
            int c = (ks * 4 + kc) ^ (row & 7);
            bf[ks][n] = *(const short8*)(Bl + row * 128 + (c << 4));
          }
        }
#pragma unroll
        for (int m = 0; m < 4; ++m) {
          int row = wm * 128 + mh * 64 + m * 16 + ar;
          int c = (ks * 4 + kc) ^ (row & 7);
          af[m] = *(const short8*)(Al + row * 128 + (c << 4));
        }
        __builtin_amdgcn_s_barrier();        // phase: reads done -> MFMA cluster
        __builtin_amdgcn_s_setprio(1);
#pragma unroll
        for (int m = 0; m < 4; ++m)
#pragma unroll
          for (int n = 0; n < 4; ++n)
            acc[mh * 4 + m][n] = __builtin_amdgcn_mfma_f32_16x16x32_bf16(
                af[m], bf[ks][n], acc[mh * 4 + m][n], 0, 0, 0);
        __builtin_amdgcn_s_setprio(0);
        __builtin_amdgcn_s_barrier();
      }
    }
  }

  // ---------------- fused epilogue: scale by scores, max over heads ----------------
  __syncthreads();                           // full drain before LDS reuse
  float* Zs = (float*)AshB;                  // 256 x 64 f32 = 64 KB
#pragma unroll
  for (int n = 0; n < 4; ++n) {
    int pl = wn * 64 + n * 16 + (l & 15);    // local permuted col, p = 4d+h
    int pg = nt0 * 256 + pl;
    int h = pl & 3;
    float bb = bias[(pg & 3) * 1024 + (pg >> 2)];
#pragma unroll
    for (int mi = 0; mi < 8; ++mi) {
      int rl = wm * 128 + mi * 16 + ((l >> 4) << 2);
#pragma unroll
      for (int r = 0; r < 4; ++r) {
        float z = s_sc[(rl + r) * 4 + h] * (acc[mi][n][r] + bb);
        z = fmaxf(z, __shfl_xor(z, 1));      // max over heads (adjacent p)
        z = fmaxf(z, __shfl_xor(z, 2));
        if ((l & 3) == 0) Zs[(rl + r) * 64 + (pl >> 2)] = z;
      }
    }
  }
  __syncthreads();
#pragma unroll
  for (int it = 0; it < 8; ++it) {           // coalesced float4 stores
    int i = it * 512 + tid;
    int row = i >> 4, d4 = i & 15;
    f32x4 v = *(const f32x4*)&Zs[row * 64 + d4 * 4];
    *(f32x4*)&Z[(m0 + row) * 1024 + nt0 * 64 + d4 * 4] = v;
  }
}

// ---------------- 128x128 GEMM, BK=64, 4 waves (m97 structure) — Q and K ----------------
// EPI 0: out bf16 = acc + bias[col]            (Q GEMM)
// EPI 1: scores[row][ntile] = sum_col (acc+bk[col]) * Qb[row][col]   (K GEMM + reduce)
template <int KD, int EPI>
__global__ __launch_bounds__(256) void gemm_k(
    const unsigned short* __restrict__ A, const unsigned short* __restrict__ Bt,
    const float* __restrict__ bias, const unsigned short* __restrict__ Qb,
    unsigned short* __restrict__ outb, float* __restrict__ sc) {
  __shared__ __align__(16) unsigned short As[128 * 64];
  __shared__ __align__(16) unsigned short Bs[128 * 64];
  __shared__ float sred[128][2];

  int tid = threadIdx.x;
  int bid = blockIdx.x;
  int ntile = bid & 3, mtile = bid >> 2;
  int l = tid & 63, wid = tid >> 6, wm = wid >> 1, wn = wid & 1;
  int m0 = mtile * 128;

  const unsigned short* Ab = A + (size_t)m0 * KD;
  const unsigned short* Bb = Bt + (size_t)ntile * 128 * KD;

  f32x4 zero = {0.f, 0.f, 0.f, 0.f};
  f32x4 acc[4][4];
#pragma unroll
  for (int m = 0; m < 4; ++m)
#pragma unroll
    for (int n = 0; n < 4; ++n) acc[m][n] = zero;

  for (int kt = 0; kt < KD / 64; ++kt) {
    const unsigned short* sA = Ab + kt * 64;
    const unsigned short* sB = Bb + kt * 64;
#pragma unroll
    for (int p = 0; p < 4; ++p) {
      int row = p * 32 + wid * 8 + (l >> 3);
      int sch = (l & 7) ^ (row & 7);
      GLL16((const char*)(sA + (size_t)row * KD) + sch * 16,
            (char*)As + p * 4096 + wid * 1024);
    }
#pragma unroll
    for (int p = 0; p < 4; ++p) {
      int row = p * 32 + wid * 8 + (l >> 3);
      int sch = (l & 7) ^ (row & 7);
      GLL16((const char*)(sB + (size_t)row * KD) + sch * 16,
            (char*)Bs + p * 4096 + wid * 1024);
    }
    __syncthreads();
#pragma unroll
    for (int ks = 0; ks < 2; ++ks) {
      short8 af[4], bfr[4];
#pragma unroll
      for (int m = 0; m < 4; ++m) {
        int row = wm * 64 + m * 16 + (l & 15);
        int kc = ks * 4 + (l >> 4);
        af[m] = *(const short8*)((const char*)As + row * 128 +
                                 ((kc ^ (row & 7)) << 4));
      }
#pragma unroll
      for (int n = 0; n < 4; ++n) {
        int row = wn * 64 + n * 16 + (l & 15);
        int kc = ks * 4 + (l >> 4);
        bfr[n] = *(const short8*)((const char*)Bs + row * 128 +
                                  ((kc ^ (row & 7)) << 4));
      }
#pragma unroll
      for (int m = 0; m < 4; ++m)
#pragma unroll
        for (int n = 0; n < 4; ++n)
          acc[m][n] = __builtin_amdgcn_mfma_f32_16x16x32_bf16(af[m], bfr[n],
                                                              acc[m][n], 0, 0, 0);
    }
    __syncthreads();
  }

  if constexpr (EPI == 0) {
#pragma unroll
    for (int n = 0; n < 4; ++n) {
      int col = ntile * 128 + wn * 64 + n * 16 + (l & 15);
      float bb = bias[col];
#pragma unroll
      for (int m = 0; m < 4; ++m) {
        int rowb = m0 + wm * 64 + m * 16 + ((l >> 4) << 2);
#pragma unroll
        for (int r = 0; r < 4; ++r)
          outb[(size_t)(rowb + r) * 512 + col] = f2b(acc[m][n][r] + bb);
      }
    }
  } else {
    float part[4][4] = {};
#pragma unroll
    for (int n = 0; n < 4; ++n) {
      int col = ntile * 128 + wn * 64 + n * 16 + (l & 15);
      float bb = bias[col];
#pragma unroll
      for (int m = 0; m < 4; ++m) {
        int rowb = m0 + wm * 64 + m * 16 + ((l >> 4) << 2);
#pragma unroll
        for (int r = 0; r < 4; ++r) {
          float kv = acc[m][n][r] + bb;
          part[m][r] += kv * b2f(Qb[(size_t)(rowb + r) * 512 + col]);
        }
      }
    }
#pragma unroll
    for (int m = 0; m < 4; ++m)
#pragma unroll
      for (int r = 0; r < 4; ++r) {
        float s = part[m][r];
        s += __shfl_xor(s, 1);
        s += __shfl_xor(s, 2);
        s += __shfl_xor(s, 4);
        s += __shfl_xor(s, 8);
        if ((l & 15) == 0)
          sred[wm * 64 + m * 16 + ((l >> 4) << 2) + r][wn] = s;
      }
    __syncthreads();
    if (tid < 128) sc[(size_t)(m0 + tid) * 4 + ntile] = sred[tid][0] + sred[tid][1];
  }
}

// ---------------- fallback (only if ws too small): fp32, correct but slow ----------------
__global__ __launch_bounds__(256) void naive_k(
    const float* __restrict__ Xd, const float* __restrict__ Xo,
    const float* __restrict__ Wq, const float* __restrict__ bq,
    const float* __restrict__ Wk, const float* __restrict__ bk,
    const float* __restrict__ Wv, const float* __restrict__ bv,
    float* __restrict__ Z) {
  int i = blockIdx.x, t = threadIdx.x;
  __shared__ float xd[1024], xo[512], s[4];
  for (int j = t; j < 1024; j += 256) xd[j] = Xd[(size_t)i * 1024 + j];
  for (int j = t; j < 512; j += 256) xo[j] = Xo[(size_t)i * 512 + j];
  if (t < 4) s[t] = 0.f;
  __syncthreads();
  for (int c = t; c < 512; c += 256) {
    float q = bq[c], k = bk[c];
    for (int j = 0; j < 512; ++j) q += xo[j] * Wq[(size_t)j * 512 + c];
    for (int j = 0; j < 1024; ++j) k += xd[j] * Wk[(size_t)j * 512 + c];
    atomicAdd(&s[c >> 7], q * k);
  }
  __syncthreads();
  for (int d = t; d < 1024; d += 256) {
    float z = -INFINITY;
    for (int h = 0; h < 4; ++h) {
      float v = bv[h * 1024 + d];
      for (int j = 0; j < 1024; ++j) v += xd[j] * Wv[(size_t)j * 4096 + h * 1024 + d];
      z = fmaxf(z, s[h] * v);
    }
    Z[(size_t)i * 1024 + d] = z;
  }
}

extern "C" void kernel_launch(void* const* d_in, const int* in_sizes, int n_in,
                              void* d_out, int out_size, void* d_ws, size_t ws_size,
                              hipStream_t stream) {
  const float* Xd = (const float*)d_in[0];
  const float* Xo = (const float*)d_in[1];
  const float* Wq = (const float*)d_in[2];
  const float* bq = (const float*)d_in[3];
  const float* Wk = (const float*)d_in[4];
  const float* bk = (const float*)d_in[5];
  const float* Wv = (const float*)d_in[6];
  const float* bv = (const float*)d_in[7];
  float* Z = (float*)d_out;
  long N = in_sizes[0] / 1024;

  size_t sz_Xd = (size_t)N * 1024 * 2, sz_Xo = (size_t)N * 512 * 2;
  size_t sz_Wq = (size_t)512 * 512 * 2, sz_Wk = (size_t)512 * 1024 * 2;
  size_t sz_Wv = (size_t)4096 * 1024 * 2;
  size_t sz_Qb = (size_t)N * 512 * 2, sz_sc = (size_t)N * 4 * 4;
  size_t o_Xo = sz_Xd, o_Wq = o_Xo + sz_Xo, o_Wk = o_Wq + sz_Wq,
         o_Wv = o_Wk + sz_Wk, o_Qb = o_Wv + sz_Wv, o_sc = o_Qb + sz_Qb;
  size_t need = o_sc + sz_sc;

  if (ws_size < need || (N % 256) != 0) {
    naive_k<<<(int)N, 256, 0, stream>>>(Xd, Xo, Wq, bq, Wk, bk, Wv, bv, Z);
    return;
  }

  char* w = (char*)d_ws;
  unsigned short* Xd_b = (unsigned short*)w;
  unsigned short* Xo_b = (unsigned short*)(w + o_Xo);
  unsigned short* Wq_t = (unsigned short*)(w + o_Wq);
  unsigned short* Wk_t = (unsigned short*)(w + o_Wk);
  unsigned short* Wv_p = (unsigned short*)(w + o_Wv);
  unsigned short* Qb   = (unsigned short*)(w + o_Qb);
  float* sc = (float*)(w + o_sc);

  conv_k<<<2048, 256, 0, stream>>>(Xd, (short8*)Xd_b, N * 1024 / 8);
  conv_k<<<2048, 256, 0, stream>>>(Xo, (short8*)Xo_b, N * 512 / 8);
  tconv_k<<<dim3(16, 16), 256, 0, stream>>>(Wq, Wq_t, 512, 512, 0);
  tconv_k<<<dim3(32, 16), 256, 0, stream>>>(Wk, Wk_t, 1024, 512, 0);
  tconv_k<<<dim3(32, 128), 256, 0, stream>>>(Wv, Wv_p, 1024, 4096, 1);

  int mt = (int)(N / 128);
  gemm_k<512, 0><<<mt * 4, 256, 0, stream>>>(Xo_b, Wq_t, bq, nullptr, Qb, nullptr);
  gemm_k<1024, 1><<<mt * 4, 256, 0, stream>>>(Xd_b, Wk_t, bk, Qb, nullptr, sc);
  gemm_v256_k<1024><<<(int)(N / 256) * 16, 512, 0, stream>>>(Xd_b, Wv_p, bv, sc, Z);
}